// Round 6
// baseline (263.390 us; speedup 1.0000x reference)
//
#include <hip/hip_runtime.h>
#include <hip/hip_bf16.h>
#include <stdint.h>

// ---------------------------------------------------------------------------
// HilbertAttention pipeline, bf16 MFMA implementation.
//   x = ([q|k|v] @ W1t^T)/3           (GEMM1 fused f32->bf16 A-staging)
//   k_fuse23: per (seg,grp,b) WG:  qkv_h = x_grp @ Wqkv_h  (h-loop)
//             -> attention (64x64)  -> out += ao_h @ Wout_h  (f32 out, direct)
// Eliminates the QKV (100MB w + 100MB r) and ATT (34+34MB) intermediates.
// All LDS tiles XOR-swizzled (T2/rule21); B-streaming with counted vmcnt (T4).
// ---------------------------------------------------------------------------

typedef __bf16 bf16_t;
typedef __bf16 bf16x8 __attribute__((ext_vector_type(8)));
typedef __bf16 bf16x4 __attribute__((ext_vector_type(4)));
typedef float  f32x4  __attribute__((ext_vector_type(4)));

#define DEVI __device__ __forceinline__
#define BAR __builtin_amdgcn_s_barrier()

static constexpr int Mtok = 16384;   // tokens per batch
static constexpr int ROWS = 32768;   // B * Mtok

DEVI void gload_lds16(const void* g, void* l) {
  __builtin_amdgcn_global_load_lds(
      (__attribute__((address_space(1))) uint32_t*)(uintptr_t)g,
      (__attribute__((address_space(3))) uint32_t*)(uint32_t)(uintptr_t)l,
      16, 0, 0);
}

// ---------------- Hilbert permutation (n = 128 grid) -----------------------
__global__ void k_perm(int* __restrict__ perm) {
  int d = blockIdx.x * 256 + threadIdx.x;
  if (d >= Mtok) return;
  int t = d, x = 0, y = 0;
  for (int s = 1; s < 128; s <<= 1) {
    int rx = (t >> 1) & 1;
    int ry = (t ^ rx) & 1;
    if (ry == 0) {
      if (rx == 1) { x = s - 1 - x; y = s - 1 - y; }
      int tmp = x; x = y; y = tmp;
    }
    x += s * rx;
    y += s * ry;
    t >>= 2;
  }
  perm[d] = y * 128 + x;
}

// ---------------- weight prep ----------------------------------------------
// W1t [512][1536] = concat_K(Wq,Wk,Wv)^T / 3
// Wqkvr[8][192][512]: per-head B^T rows (0-63 q, 64-127 k, 128-191 v), k-contig
// Woutt [512][512] = Wout^T
__global__ void k_prep_w(const float* __restrict__ Wq, const float* __restrict__ Wk,
                         const float* __restrict__ Wv, const float* __restrict__ Wqkv,
                         const float* __restrict__ Wout,
                         bf16_t* __restrict__ W1t, bf16_t* __restrict__ Wqkvr,
                         bf16_t* __restrict__ Woutt) {
  const int tid = blockIdx.x * 256 + threadIdx.x;
  const int stride = gridDim.x * 256;
  for (int i = tid; i < 512 * 1536; i += stride) {
    int n = i / 1536, kk = i % 1536;
    const float* W = (kk < 512) ? Wq : (kk < 1024 ? Wk : Wv);
    W1t[i] = (bf16_t)(W[(kk & 511) * 512 + n] * (1.0f / 3.0f));
  }
  for (int i = tid; i < 8 * 192 * 512; i += stride) {
    int h = i / (192 * 512);
    int rem = i % (192 * 512);
    int row = rem / 512, kk = rem % 512;
    int gsel = row >> 6, c = row & 63;
    Wqkvr[i] = (bf16_t)Wqkv[kk * 1536 + gsel * 512 + h * 64 + c];
  }
  for (int i = tid; i < 512 * 512; i += stride) {
    int n = i / 512, kk = i % 512;
    Woutt[i] = (bf16_t)Wout[kk * 512 + n];
  }
}

// ---------------- staging helpers (GEMM1) -----------------------------------
DEVI void stageB(const bf16_t* Bb, int Kdim, int k0, bf16_t* dst, int qsel,
                 int tid, int cswz) {
  int r = tid >> 3;
  int rb0 = (r >> 5) * 64 + qsel * 32 + (r & 31);
  const bf16_t* g = Bb + (long)rb0 * Kdim + k0 + cswz * 8;
  gload_lds16(g, dst + rb0 * 64 + (tid & 7) * 8);
  gload_lds16(g + (long)128 * Kdim, dst + (rb0 + 128) * 64 + (tid & 7) * 8);
}

#define LOAD_AF(AF, QM, BUF)                                                   \
  _Pragma("unroll") for (int m = 0; m < 4; m++) {                              \
    int row = wm * 128 + (QM) * 64 + m * 16 + l15;                             \
    AF[m][0] = *(const bf16x8*)((BUF) + row * 64 + cb0 * 8);                   \
    AF[m][1] = *(const bf16x8*)((BUF) + row * 64 + cb1 * 8);                   \
  }
#define LOAD_BG(BG, QN, BUF)                                                   \
  _Pragma("unroll") for (int n = 0; n < 2; n++) {                              \
    int row = wn * 64 + (QN) * 32 + n * 16 + l15;                              \
    BG[n][0] = *(const bf16x8*)((BUF) + row * 64 + cb0 * 8);                   \
    BG[n][1] = *(const bf16x8*)((BUF) + row * 64 + cb1 * 8);                   \
  }
#define QUAD(QM, QN, AF, BG)                                                   \
  do {                                                                         \
    __builtin_amdgcn_s_setprio(1);                                             \
    _Pragma("unroll") for (int kh = 0; kh < 2; kh++)                           \
    _Pragma("unroll") for (int m = 0; m < 4; m++)                              \
    _Pragma("unroll") for (int n = 0; n < 2; n++)                              \
      acc[(QM)*4+m][(QN)*2+n] = __builtin_amdgcn_mfma_f32_16x16x32_bf16(       \
          AF[m][kh], BG[n][kh], acc[(QM)*4+m][(QN)*2+n], 0, 0, 0);             \
    __builtin_amdgcn_s_setprio(0);                                             \
  } while (0)

// ---------------- GEMM1 fused: A = [q|k|v] f32, converted in-kernel --------
DEVI const float* selsrc(int tt, const float* q, const float* k, const float* v) {
  return tt < 8 ? q : (tt < 16 ? k : v);
}

DEVI void loadAh(const float* S, long grow, int colf, float4* pa) {
  const float* p0 = S + grow * 512 + colf;
  pa[0] = *(const float4*)(p0);
  pa[1] = *(const float4*)(p0 + 4);
  const float* p1 = p0 + 128 * 512;
  pa[2] = *(const float4*)(p1);
  pa[3] = *(const float4*)(p1 + 4);
}

DEVI void writeAh(bf16_t* dst, int rbase, int cbt, const float4* pa) {
  bf16x8 o0, o1;
  o0[0] = (bf16_t)pa[0].x; o0[1] = (bf16_t)pa[0].y; o0[2] = (bf16_t)pa[0].z; o0[3] = (bf16_t)pa[0].w;
  o0[4] = (bf16_t)pa[1].x; o0[5] = (bf16_t)pa[1].y; o0[6] = (bf16_t)pa[1].z; o0[7] = (bf16_t)pa[1].w;
  o1[0] = (bf16_t)pa[2].x; o1[1] = (bf16_t)pa[2].y; o1[2] = (bf16_t)pa[2].z; o1[3] = (bf16_t)pa[2].w;
  o1[4] = (bf16_t)pa[3].x; o1[5] = (bf16_t)pa[3].y; o1[6] = (bf16_t)pa[3].z; o1[7] = (bf16_t)pa[3].w;
  int sw = (cbt ^ (rbase & 7)) * 8;
  *(bf16x8*)(dst + rbase * 64 + sw) = o0;
  *(bf16x8*)(dst + (rbase + 128) * 64 + sw) = o1;
}

__global__ __launch_bounds__(512, 2) void k_gemm1f(const float* __restrict__ q,
                                                   const float* __restrict__ k,
                                                   const float* __restrict__ v,
                                                   const bf16_t* __restrict__ Bt,
                                                   bf16_t* __restrict__ Cb,
                                                   int Ndim) {
  constexpr int Kdim = 1536;
  constexpr int NT = 24;
  __shared__ bf16_t lds[4 * 16384];  // 128 KiB
  const int tid = threadIdx.x;
  const int lane = tid & 63, w = tid >> 6;
  const int wm = w >> 2, wn = w & 3;
  const int l15 = lane & 15, l4 = lane >> 4;
  const int cb0 = l4 ^ (l15 & 7), cb1 = cb0 ^ 4;
  const int cswz = (tid & 7) ^ ((tid >> 3) & 7);
  const int cbt = tid & 7, rA = tid >> 3;
  const long arow0 = (long)blockIdx.y * 256;
  const long bcol0 = (long)blockIdx.x * 256;
  const bf16_t* Bb = Bt + bcol0 * Kdim;

  bf16_t* Acur = lds;
  bf16_t* Bcur = lds + 16384;
  bf16_t* Anxt = lds + 32768;
  bf16_t* Bnxt = lds + 49152;

  f32x4 acc[8][4] = {};
  float4 pa0[4], pa1[4];

  // ---- prologue ----
  loadAh(selsrc(0, q, k, v), arow0 + rA,      (cbt << 3), pa0);
  loadAh(selsrc(0, q, k, v), arow0 + rA + 64, (cbt << 3), pa1);
  writeAh(Acur, rA,      cbt, pa0);
  writeAh(Acur, rA + 64, cbt, pa1);
  stageB(Bb, Kdim, 0, Bcur, 0, tid, cswz);   // Bn0(0)
  stageB(Bb, Kdim, 0, Bcur, 1, tid, cswz);   // Bn1(0)
  loadAh(selsrc(1, q, k, v), arow0 + rA, 64 + (cbt << 3), pa0);  // Aq0(1)
  writeAh(Anxt, rA, cbt, pa0);                                    // -> nxt
  stageB(Bb, Kdim, 64, Bnxt, 1, tid, cswz);  // Bn1(1) -> nxt
  loadAh(selsrc(1, q, k, v), arow0 + rA + 64,  64 + (cbt << 3), pa1);  // Aq1(1)
  loadAh(selsrc(2, q, k, v), arow0 + rA,      128 + (cbt << 3), pa0);  // Aq0(2)
  asm volatile("s_waitcnt vmcnt(18)" ::: "memory");
  asm volatile("s_waitcnt lgkmcnt(0)" ::: "memory");
  BAR;

  for (int t = 0; t < NT; t++) {
    bf16x8 af[4][2], bg0[2][2], bg1[2][2];
    // P1 (q0,n0): stage Bn0(t+1)->nxt
    LOAD_AF(af, 0, Acur);
    LOAD_BG(bg0, 0, Bcur);
    if (t + 1 < NT) stageB(Bb, Kdim, (t + 1) * 64, Bnxt, 0, tid, cswz);
    BAR;
    QUAD(0, 0, af, bg0);
    BAR;
    // P2 (q0,n1): write Aq1(t+1)->nxt, then load pa1 <- Aq1(t+2)
    LOAD_BG(bg1, 1, Bcur);
    if (t + 1 < NT) writeAh(Anxt, rA + 64, cbt, pa1);
    if (t + 2 < NT) loadAh(selsrc(t + 2, q, k, v), arow0 + rA + 64,
                           (((t + 2) & 7) << 6) + (cbt << 3), pa1);
    BAR;
    QUAD(0, 1, af, bg1);
    BAR;
    // P3 (q1,n1): write Aq0(t+2)->cur, load pa0 <- Aq0(t+3)
    LOAD_AF(af, 1, Acur);
    if (t + 2 < NT) writeAh(Acur, rA, cbt, pa0);
    if (t + 3 < NT) loadAh(selsrc(t + 3, q, k, v), arow0 + rA,
                           (((t + 3) & 7) << 6) + (cbt << 3), pa0);
    BAR;
    QUAD(1, 1, af, bg1);
    BAR;
    // P4 (q1,n0): stage Bn1(t+2)->cur
    LOAD_BG(bg0, 0, Bcur);
    if (t + 2 < NT) stageB(Bb, Kdim, (t + 2) * 64, Bcur, 1, tid, cswz);
    BAR;
    QUAD(1, 0, af, bg0);
    if (t + 3 < NT)      { asm volatile("s_waitcnt vmcnt(18)" ::: "memory"); }
    else if (t + 2 < NT) { asm volatile("s_waitcnt vmcnt(10)" ::: "memory"); }
    else                 { asm volatile("s_waitcnt vmcnt(0)"  ::: "memory"); }
    asm volatile("s_waitcnt lgkmcnt(0)" ::: "memory");
    BAR;
    bf16_t* tA = Acur; Acur = Anxt; Anxt = tA;
    bf16_t* tB = Bcur; Bcur = Bnxt; Bnxt = tB;
  }

  // epilogue: C-write (bf16)
#pragma unroll
  for (int i = 0; i < 8; i++) {
#pragma unroll
    for (int j = 0; j < 4; j++) {
      long row = arow0 + wm * 128 + i * 16 + l4 * 4;
      long col = bcol0 + wn * 64 + j * 16 + l15;
#pragma unroll
      for (int r = 0; r < 4; r++)
        Cb[(row + r) * Ndim + col] = (bf16_t)acc[i][j][r];
    }
  }
}

// ---------------- fused GEMM2 + attention + GEMM3 --------------------------
// One WG per (seg n, grp g, batch b): 64 tokens (dilation group), all 8 heads.
//   Xl[64][512]   : gathered x rows, chunk-XOR swizzled (64 chunks of 8)
//   Bd[2][192][64]: per-K-step Wqkv B-slice, dbuf, counted vmcnt(3)
//   Ql/Kl/VT/Pl/Ol[64][64]: 8KB transpose tiles, chunk-XOR (8 chunks of 8)
// per head: qkv (8 K-steps) -> write Ql/Kl/VT -> QK+softmax+PV (waves 0-3)
//           -> Ol -> out_acc += Ol @ Woutt[:, h*64:+64]  (B-frags from L2)
// epilogue: out rows scattered by perm (f32, coalesced 64B per quarter-wave).
__global__ __launch_bounds__(512, 2) void k_fuse23(const bf16_t* __restrict__ X,
                                                   const bf16_t* __restrict__ Wqkvr,
                                                   const bf16_t* __restrict__ Woutt,
                                                   const int* __restrict__ perm,
                                                   float* __restrict__ out) {
  __shared__ bf16_t Xl[64 * 512];       // 64 KiB
  __shared__ bf16_t Bd[2][192 * 64];    // 48 KiB
  __shared__ bf16_t Ql[64 * 64], Kl[64 * 64], VT[64 * 64], Pl[64 * 64], Ol[64 * 64];
  __shared__ int perml[64];
  const int n = blockIdx.x, g = blockIdx.y, b = blockIdx.z;
  const int tid = threadIdx.x;
  const int lane = tid & 63, w = tid >> 6;
  const int l15 = lane & 15, l4 = lane >> 4;

  if (tid < 64) perml[tid] = perm[n * 128 + tid * 2 + g];
  __syncthreads();

  // ---- stage Xl (gathered rows, pre-swizzled source) ----
#pragma unroll
  for (int j = 0; j < 8; j++) {
    int cc = tid + j * 512;           // 0..4095
    int s = cc >> 6, ch = cc & 63;
    const bf16_t* src = X + ((long)(b * Mtok + perml[s])) * 512 + ((ch ^ (s & 7)) * 8);
    gload_lds16(src, Xl + cc * 8);
  }

  f32x4 oacc3[4][4] = {};  // out_acc: rows 64 x cols [w*64, w*64+64)

  // GEMM2 wave split: rows (w&1)*32 (2 rf), cols (w>>1)*48 (3 cf)
  const int r2base = (w & 1) * 32;
  const int c2base = (w >> 1) * 48;

  for (int h = 0; h < 8; h++) {
    // ---- qkv_h = Xl @ Wqkvr[h]^T : out [64 rows][192 cols] ----
    f32x4 facc[2][3] = {};
    {
      // stage K-step 0
      const bf16_t* Wh = Wqkvr + (long)h * 192 * 512;
#pragma unroll
      for (int j = 0; j < 3; j++) {
        int cc = tid + j * 512;       // 0..1535
        int row = cc >> 3, ch = cc & 7;
        gload_lds16(Wh + row * 512 + ((ch ^ (row & 7)) * 8), Bd[0] + cc * 8);
      }
      for (int kk = 0; kk < 8; kk++) {
        bf16_t* curB = Bd[kk & 1];
        if (kk < 7) {
          bf16_t* nxtB = Bd[(kk & 1) ^ 1];
#pragma unroll
          for (int j = 0; j < 3; j++) {
            int cc = tid + j * 512;
            int row = cc >> 3, ch = cc & 7;
            gload_lds16(Wh + row * 512 + (kk + 1) * 64 + ((ch ^ (row & 7)) * 8),
                        nxtB + cc * 8);
          }
          asm volatile("s_waitcnt vmcnt(3)" ::: "memory");
        } else {
          asm volatile("s_waitcnt vmcnt(0)" ::: "memory");
        }
        __syncthreads();
        bf16x8 af[2][2], bg[3][2];
#pragma unroll
        for (int rf = 0; rf < 2; rf++) {
          int row = r2base + rf * 16 + l15;
#pragma unroll
          for (int sub = 0; sub < 2; sub++) {
            int ch = (kk * 8 + sub * 4 + l4) ^ (row & 7);
            af[rf][sub] = *(const bf16x8*)(Xl + row * 64 * 8 / 8 * 8 + 0);  // placeholder
          }
        }
        // (real loads below — explicit addressing)
#pragma unroll
        for (int rf = 0; rf < 2; rf++) {
          int row = r2base + rf * 16 + l15;
#pragma unroll
          for (int sub = 0; sub < 2; sub++) {
            int ch = (kk * 8 + sub * 4 + l4) ^ (row & 7);
            af[rf][sub] = *(const bf16x8*)(Xl + (row * 64 + ch) * 8);
          }
        }
#pragma unroll
        for (int cf = 0; cf < 3; cf++) {
          int row = c2base + cf * 16 + l15;
#pragma unroll
          for (int sub = 0; sub < 2; sub++) {
            int ch = (sub * 4 + l4) ^ (row & 7);
            bg[cf][sub] = *(const bf16x8*)(curB + (row * 8 + ch) * 8);
          }
        }
#pragma unroll
        for (int rf = 0; rf < 2; rf++)
#pragma unroll
          for (int cf = 0; cf < 3; cf++)
#pragma unroll
            for (int sub = 0; sub < 2; sub++)
              facc[rf][cf] = __builtin_amdgcn_mfma_f32_16x16x32_bf16(
                  af[rf][sub], bg[cf][sub], facc[rf][cf], 0, 0, 0);
        __syncthreads();
      }
    }

    // ---- scatter qkv acc -> Ql / Kl / VT (bf16, chunk-XOR) ----
#pragma unroll
    for (int rf = 0; rf < 2; rf++) {
      int t0 = r2base + rf * 16 + l4 * 4;
#pragma unroll
      for (int cf = 0; cf < 3; cf++) {
        int c = c2base + cf * 16 + l15;   // frag never straddles 64-boundaries
        if (c < 64) {
#pragma unroll
          for (int r = 0; r < 4; r++) {
            int t = t0 + r;
            Ql[t * 64 + (((c >> 3) ^ (t & 7)) * 8) + (c & 7)] = (bf16_t)facc[rf][cf][r];
          }
        } else if (c < 128) {
          int ck = c - 64;
#pragma unroll
          for (int r = 0; r < 4; r++) {
            int t = t0 + r;
            Kl[t * 64 + (((ck >> 3) ^ (t & 7)) * 8) + (ck & 7)] = (bf16_t)facc[rf][cf][r];
          }
        } else {
          int d = c - 128;
          bf16x4 pk;
          pk[0] = (bf16_t)facc[rf][cf][0]; pk[1] = (bf16_t)facc[rf][cf][1];
          pk[2] = (bf16_t)facc[rf][cf][2]; pk[3] = (bf16_t)facc[rf][cf][3];
          *(bf16x4*)(VT + d * 64 + (((t0 >> 3) ^ (d & 7)) * 8) + (t0 & 7)) = pk;
        }
      }
    }
    __syncthreads();

    // ---- attention (waves 0-3: 16 rows each) ----
    if (w < 4) {
      f32x4 sc[4] = {};
#pragma unroll
      for (int ks = 0; ks < 2; ks++) {
        int tq = w * 16 + l15;
        bf16x8 aq = *(const bf16x8*)(Ql + (tq * 8 + (((ks * 4 + l4) ^ (tq & 7)))) * 8);
#pragma unroll
        for (int cf = 0; cf < 4; cf++) {
          int s = cf * 16 + l15;
          bf16x8 bk = *(const bf16x8*)(Kl + (s * 8 + ((ks * 4 + l4) ^ (s & 7))) * 8);
          sc[cf] = __builtin_amdgcn_mfma_f32_16x16x32_bf16(aq, bk, sc[cf], 0, 0, 0);
        }
      }
      const float scale = 0.125f;
#pragma unroll
      for (int r = 0; r < 4; r++) {
        float mx = fmaxf(fmaxf(sc[0][r], sc[1][r]), fmaxf(sc[2][r], sc[3][r]));
        mx = fmaxf(mx, __shfl_xor(mx, 1, 64));
        mx = fmaxf(mx, __shfl_xor(mx, 2, 64));
        mx = fmaxf(mx, __shfl_xor(mx, 4, 64));
        mx = fmaxf(mx, __shfl_xor(mx, 8, 64));
        float p0 = __expf((sc[0][r] - mx) * scale);
        float p1 = __expf((sc[1][r] - mx) * scale);
        float p2 = __expf((sc[2][r] - mx) * scale);
        float p3 = __expf((sc[3][r] - mx) * scale);
        float sum = p0 + p1 + p2 + p3;
        sum += __shfl_xor(sum, 1, 64);
        sum += __shfl_xor(sum, 2, 64);
        sum += __shfl_xor(sum, 4, 64);
        sum += __shfl_xor(sum, 8, 64);
        float inv = 1.0f / sum;
        int t = w * 16 + l4 * 4 + r;
        float pv[4] = {p0, p1, p2, p3};
#pragma unroll
        for (int cf = 0; cf < 4; cf++) {
          int s = cf * 16 + l15;
          Pl[t * 64 + (((s >> 3) ^ (t & 7)) * 8) + (s & 7)] = (bf16_t)(pv[cf] * inv);
        }
      }
    }
    __syncthreads();
    if (w < 4) {
      f32x4 po[4] = {};
#pragma unroll
      for (int ks = 0; ks < 2; ks++) {
        int tq = w * 16 + l15;
        bf16x8 ap = *(const bf16x8*)(Pl + (tq * 8 + ((ks * 4 + l4) ^ (tq & 7))) * 8);
#pragma unroll
        for (int cf = 0; cf < 4; cf++) {
          int d = cf * 16 + l15;
          bf16x8 bv = *(const bf16x8*)(VT + (d * 8 + ((ks * 4 + l4) ^ (d & 7))) * 8);
          po[cf] = __builtin_amdgcn_mfma_f32_16x16x32_bf16(ap, bv, po[cf], 0, 0, 0);
        }
      }
      // Ol[t][d], chunk-XOR on d
#pragma unroll
      for (int cf = 0; cf < 4; cf++) {
        int d = cf * 16 + l15;
#pragma unroll
        for (int r = 0; r < 4; r++) {
          int t = w * 16 + l4 * 4 + r;
          Ol[t * 64 + (((d >> 3) ^ (t & 7)) * 8) + (d & 7)] = (bf16_t)po[cf][r];
        }
      }
    }
    __syncthreads();

    // ---- out_acc += Ol @ Woutt[:, h*64:+64] (all 8 waves; B from global) ----
#pragma unroll
    for (int ks = 0; ks < 2; ks++) {
      bf16x8 af3[4], bg3[4];
#pragma unroll
      for (int rf = 0; rf < 4; rf++) {
        int t = rf * 16 + l15;
        af3[rf] = *(const bf16x8*)(Ol + (t * 8 + ((ks * 4 + l4) ^ (t & 7))) * 8);
      }
#pragma unroll
      for (int cf = 0; cf < 4; cf++) {
        int c = w * 64 + cf * 16 + l15;
        bg3[cf] = *(const bf16x8*)(Woutt + (long)c * 512 + h * 64 + ks * 32 + l4 * 8);
      }
#pragma unroll
      for (int rf = 0; rf < 4; rf++)
#pragma unroll
        for (int cf = 0; cf < 4; cf++)
          oacc3[rf][cf] = __builtin_amdgcn_mfma_f32_16x16x32_bf16(
              af3[rf], bg3[cf], oacc3[rf][cf], 0, 0, 0);
    }
  }

  // ---- epilogue: scatter out rows by perm (f32 direct) ----
#pragma unroll
  for (int rf = 0; rf < 4; rf++) {
#pragma unroll
    for (int r = 0; r < 4; r++) {
      int t = rf * 16 + l4 * 4 + r;
      long orow = (long)(b * Mtok + perml[t]) * 512 + w * 64;
#pragma unroll
      for (int cf = 0; cf < 4; cf++)
        out[orow + cf * 16 + l15] = oacc3[rf][cf][r];
    }
  }
}

// ---------------------------------------------------------------------------
extern "C" void kernel_launch(void* const* d_in, const int* in_sizes, int n_in,
                              void* d_out, int out_size, void* d_ws, size_t ws_size,
                              hipStream_t stream) {
  const float* q    = (const float*)d_in[0];
  const float* k    = (const float*)d_in[1];
  const float* v    = (const float*)d_in[2];
  const float* Wq   = (const float*)d_in[3];
  const float* Wk   = (const float*)d_in[4];
  const float* Wv   = (const float*)d_in[5];
  const float* Wqkv = (const float*)d_in[6];
  const float* Wout = (const float*)d_in[7];

  char* ws = (char*)d_ws;
  const size_t X_BYTES = (size_t)ROWS * 512 * 2;   // 33,554,432
  bf16_t* X     = (bf16_t*)ws;
  bf16_t* W1t   = (bf16_t*)(ws + X_BYTES);
  bf16_t* Wqkvr = W1t + 512 * 1536;
  bf16_t* Woutt = Wqkvr + 8 * 192 * 512;
  int*    perm  = (int*)(Woutt + 512 * 512);

  k_perm<<<64, 256, 0, stream>>>(perm);
  k_prep_w<<<512, 256, 0, stream>>>(Wq, Wk, Wv, Wqkv, Wout, W1t, Wqkvr, Woutt);
  // GEMM1 (fused f32->bf16): X = [q|k|v] @ W1 (M=32768, N=512, K=1536)
  k_gemm1f<<<dim3(2, 128), 512, 0, stream>>>(q, k, v, W1t, X, 512);
  // fused GEMM2 + attention + GEMM3 -> out (f32)
  k_fuse23<<<dim3(128, 2, 2), 512, 0, stream>>>(X, Wqkvr, Woutt, perm, (float*)d_out);
}